// Round 5
// baseline (237.167 us; speedup 1.0000x reference)
//
#include <hip/hip_runtime.h>
#include <math.h>
#include <stdint.h>

// ContrastiveLoss: N=8192, C=512, NC=100, MARGIN=1.0
// loss = (sum_{i!=j,same} d_ij + sum_{i!=j,diff} max(0, 1-sqrt(d_ij))^2) / (2*N*(N-1))
// d_ij = |xi|^2+|xj|^2-2 xi.xj (clamped at 0).
//
// Round 5: positive term via class sums computed with FIXED-POINT INT64
// ATOMICS (integer add commutes -> bit-deterministic, no sort/bins needed):
//   positive = sum_c [ 2 n_c S2_c - 2 |M_c|^2 ],  M in Q30, S2 in Q20.
// One fused pass reads f once (sq32, bf16[0:32), M/S2/n atomics).
// Negative term: K=32 bf16-MFMA lower-bound screen (thr 2.0 covers bf16
// rounding), exact fp32 recompute for rare candidates. No fp atomics anywhere.

static constexpr int   Nn  = 8192;
static constexpr int   Cc  = 512;
static constexpr float MRG = 1.0f;
static constexpr int   KF  = 32;          // filter features
static constexpr float FILT_THR = 2.0f;   // margin^2 + bf16-error slack

static constexpr int NBLK2   = Nn / 128;                  // 64
static constexpr int NPAIRS2 = NBLK2 * (NBLK2 + 1) / 2;   // 2080
static constexpr int NCLS    = 100;
static constexpr int NBINS   = NCLS * Cc;                 // 51200 (M bins)

static constexpr float SCALE_M  = 1073741824.0f;  // 2^30
static constexpr float SCALE_S2 = 1048576.0f;     // 2^20

// ---- fp32 fallback config (small-ws path) ----
static constexpr int BM1     = 64;
static constexpr int BK1     = 32;
static constexpr int NBLK1   = Nn / BM1;
static constexpr int NPAIRS1 = NBLK1 * (NBLK1 + 1) / 2;
static constexpr int LSTR    = 68;

typedef __attribute__((ext_vector_type(8))) short short8v;
typedef __attribute__((ext_vector_type(4))) float f32x4;

static __device__ inline unsigned short f2bf(float x) {
    unsigned u = __float_as_uint(x);
    unsigned rnd = 0x7FFFu + ((u >> 16) & 1u);
    return (unsigned short)((u + rnd) >> 16);
}

static __device__ inline void atomAddI64(long long* p, long long v) {
    atomicAdd((unsigned long long*)p, (unsigned long long)v);
}

// ---------------------------------------------------------------- zero accumulators
__global__ __launch_bounds__(256) void zero_kernel(long long* __restrict__ bins,  // Mfix||s2fix
                                                   int* __restrict__ cnt) {
    const int i = blockIdx.x * 256 + threadIdx.x;
    if (i < NBINS + NCLS) bins[i] = 0LL;
    if (i < NCLS) cnt[i] = 0;
}

// ---------------------------------------------------------------- fused prep pass
// 4 waves/block, one row per wave. Reads f once (16 MB):
//  - sq32[row], fb32[row][0:32) bf16
//  - Mfix[c][d] += x*2^30 (int64 atomics), s2fix[c] += |x|^2*2^20, cnt[c]++
__global__ __launch_bounds__(256) void prep_kernel(const float* __restrict__ f,
                                                   const int* __restrict__ tgt,
                                                   unsigned short* __restrict__ fb32,
                                                   float* __restrict__ sq32,
                                                   long long* __restrict__ Mfix,
                                                   long long* __restrict__ s2fix,
                                                   int* __restrict__ cnt) {
    const int wave = threadIdx.x >> 6;
    const int lane = threadIdx.x & 63;
    const int row  = blockIdx.x * 4 + wave;
    const int c    = tgt[row];                       // broadcast load per wave
    const float4* rp = reinterpret_cast<const float4*>(f + (size_t)row * Cc);
    float4 v0 = rp[lane * 2 + 0];
    float4 v1 = rp[lane * 2 + 1];

    // fixed-point class-mean contributions (8 dims per lane)
    long long* mrow = Mfix + (size_t)c * Cc + lane * 8;
    atomAddI64(mrow + 0, (long long)(v0.x * SCALE_M));
    atomAddI64(mrow + 1, (long long)(v0.y * SCALE_M));
    atomAddI64(mrow + 2, (long long)(v0.z * SCALE_M));
    atomAddI64(mrow + 3, (long long)(v0.w * SCALE_M));
    atomAddI64(mrow + 4, (long long)(v1.x * SCALE_M));
    atomAddI64(mrow + 5, (long long)(v1.y * SCALE_M));
    atomAddI64(mrow + 6, (long long)(v1.z * SCALE_M));
    atomAddI64(mrow + 7, (long long)(v1.w * SCALE_M));

    float s8 = v0.x * v0.x + v0.y * v0.y + v0.z * v0.z + v0.w * v0.w +
               v1.x * v1.x + v1.y * v1.y + v1.z * v1.z + v1.w * v1.w;

    if (lane < 4) {   // first 32 features -> bf16 for the filter
        short8v o;
        o[0] = (short)f2bf(v0.x); o[1] = (short)f2bf(v0.y);
        o[2] = (short)f2bf(v0.z); o[3] = (short)f2bf(v0.w);
        o[4] = (short)f2bf(v1.x); o[5] = (short)f2bf(v1.y);
        o[6] = (short)f2bf(v1.z); o[7] = (short)f2bf(v1.w);
        *reinterpret_cast<short8v*>(fb32 + (size_t)row * KF + lane * 8) = o;
    }

    float sAll = s8;
    float s32  = (lane < 4) ? s8 : 0.0f;
    #pragma unroll
    for (int off = 32; off > 0; off >>= 1) {
        sAll += __shfl_down(sAll, off, 64);
        s32  += __shfl_down(s32,  off, 64);
    }
    if (lane == 0) {
        sq32[row] = s32;
        atomAddI64(s2fix + c, (long long)(sAll * SCALE_S2));
        atomicAdd(cnt + c, 1);
    }
}

// ---------------------------------------------------------------- sum_c |M_c|^2 partials
__global__ __launch_bounds__(256) void msq_kernel(const long long* __restrict__ Mfix,
                                                  double* __restrict__ msqPart) {
    __shared__ double red[256];
    double local = 0.0;
    const int base = blockIdx.x * 800;            // 64 blocks x 800 = 51200 bins
    #pragma unroll
    for (int it = 0; it < 4; ++it) {
        const int idx = base + it * 256 + threadIdx.x;
        if (idx < base + 800 && idx < NBINS) {
            const double m = (double)Mfix[idx] * (1.0 / (double)SCALE_M);
            local += m * m;
        }
    }
    red[threadIdx.x] = local;
    __syncthreads();
    #pragma unroll
    for (int st = 128; st > 0; st >>= 1) {
        if (threadIdx.x < st) red[threadIdx.x] += red[threadIdx.x + st];
        __syncthreads();
    }
    if (threadIdx.x == 0) msqPart[blockIdx.x] = red[0];
}

// ---------------------------------------------------------------- hinge screen (K=32 bf16 MFMA)
__global__ __launch_bounds__(256) void filter_kernel(const unsigned short* __restrict__ fb32,
                                                     const float* __restrict__ f,
                                                     const int* __restrict__ tgt,
                                                     const float* __restrict__ sq32,
                                                     double* __restrict__ negPart) {
    int rem = blockIdx.x, br = 0;
    while (rem >= NBLK2 - br) { rem -= NBLK2 - br; ++br; }
    const int bc = br + rem;

    __shared__ unsigned short As[128][40];   // 80B row stride: bank-spread, 16B aligned
    __shared__ unsigned short Bs[128][40];

    const int tid  = threadIdx.x;
    const int lane = tid & 63;
    const int wid  = tid >> 6;
    const int wr   = wid >> 1;
    const int wc   = wid & 1;

    #pragma unroll
    for (int it = 0; it < 2; ++it) {
        const int s   = tid + it * 256;     // 512 slots of 16B
        const int row = s >> 2, q = s & 3;
        short8v va = *reinterpret_cast<const short8v*>(fb32 + (size_t)(br * 128 + row) * KF + q * 8);
        short8v vb = *reinterpret_cast<const short8v*>(fb32 + (size_t)(bc * 128 + row) * KF + q * 8);
        *reinterpret_cast<short8v*>(&As[row][q * 8]) = va;
        *reinterpret_cast<short8v*>(&Bs[row][q * 8]) = vb;
    }
    __syncthreads();

    const f32x4 zero = {0.f, 0.f, 0.f, 0.f};
    short8v a[4], b[4];
    #pragma unroll
    for (int mf = 0; mf < 4; ++mf) {
        const int row = wr * 64 + mf * 16 + (lane & 15);
        a[mf] = *reinterpret_cast<const short8v*>(&As[row][(lane >> 4) * 8]);
    }
    #pragma unroll
    for (int nf = 0; nf < 4; ++nf) {
        const int row = wc * 64 + nf * 16 + (lane & 15);
        b[nf] = *reinterpret_cast<const short8v*>(&Bs[row][(lane >> 4) * 8]);
    }
    f32x4 acc[4][4];
    #pragma unroll
    for (int mf = 0; mf < 4; ++mf)
        #pragma unroll
        for (int nf = 0; nf < 4; ++nf)
            acc[mf][nf] = __builtin_amdgcn_mfma_f32_16x16x32_bf16(a[mf], b[nf], zero, 0, 0, 0);

    const int gi0 = br * 128 + wr * 64;
    const int gj0 = bc * 128 + wc * 64;

    float s32i[16]; int ti[16];
    #pragma unroll
    for (int mf = 0; mf < 4; ++mf)
        #pragma unroll
        for (int j = 0; j < 4; ++j) {
            const int r = gi0 + mf * 16 + (lane >> 4) * 4 + j;
            s32i[mf * 4 + j] = sq32[r];
            ti[mf * 4 + j]   = tgt[r];
        }
    float s32j[4]; int tj[4];
    #pragma unroll
    for (int nf = 0; nf < 4; ++nf) {
        const int c = gj0 + nf * 16 + (lane & 15);
        s32j[nf] = sq32[c];
        tj[nf]   = tgt[c];
    }

    float neg = 0.0f;
    #pragma unroll
    for (int mf = 0; mf < 4; ++mf)
        #pragma unroll
        for (int nf = 0; nf < 4; ++nf)
            #pragma unroll
            for (int j = 0; j < 4; ++j) {
                const int r = gi0 + mf * 16 + (lane >> 4) * 4 + j;
                const int c = gj0 + nf * 16 + (lane & 15);
                const float d32 = s32i[mf * 4 + j] + s32j[nf] - 2.0f * acc[mf][nf][j];
                if (r != c && ti[mf * 4 + j] != tj[nf] && d32 < FILT_THR) {
                    // exact full distance (fp32), rare path
                    const float4* xr = reinterpret_cast<const float4*>(f + (size_t)r * Cc);
                    const float4* xc = reinterpret_cast<const float4*>(f + (size_t)c * Cc);
                    float dd = 0.0f;
                    for (int k = 0; k < Cc / 4; ++k) {
                        float4 aa = xr[k], bb = xc[k];
                        float dx = aa.x - bb.x, dy = aa.y - bb.y;
                        float dz = aa.z - bb.z, dw = aa.w - bb.w;
                        dd += dx * dx + dy * dy + dz * dz + dw * dw;
                    }
                    const float t = (dd > 0.0f) ? (MRG - sqrtf(dd)) : MRG;
                    if (t > 0.0f) neg += t * t;
                }
            }

    __syncthreads();
    float* red = reinterpret_cast<float*>(As);
    const float w = (br == bc) ? 1.0f : 2.0f;
    red[tid] = w * neg;
    __syncthreads();
    #pragma unroll
    for (int st = 128; st > 0; st >>= 1) {
        if (tid < st) red[tid] += red[tid + st];
        __syncthreads();
    }
    if (tid == 0) negPart[blockIdx.x] = (double)red[0];
}

// ---------------------------------------------------------------- final combine
__global__ __launch_bounds__(256) void finish2_kernel(const int* __restrict__ cnt,
                                                      const long long* __restrict__ s2fix,
                                                      const double* __restrict__ msqPart,
                                                      const double* __restrict__ negPart,
                                                      float* __restrict__ out) {
    __shared__ double red[256];
    const int t = threadIdx.x;
    double pa = 0.0;
    if (t < NCLS) {
        const double n  = (double)cnt[t];
        const double s2 = (double)s2fix[t] * (1.0 / (double)SCALE_S2);
        pa = 2.0 * n * s2;
    }
    double msum = (t < 64) ? msqPart[t] : 0.0;
    double nsum = 0.0;
    for (int i = t; i < NPAIRS2; i += 256) nsum += negPart[i];
    red[t] = pa - 2.0 * msum + nsum;
    __syncthreads();
    #pragma unroll
    for (int st = 128; st > 0; st >>= 1) {
        if (t < st) red[t] += red[t + st];
        __syncthreads();
    }
    if (t == 0) {
        const double T = (double)Nn * (double)(Nn - 1);
        out[0] = (float)(red[0] / (2.0 * T));
    }
}

// ---------------------------------------------------------------- fp32 fallback (round 1)
__global__ __launch_bounds__(256) void sq_kernel(const float* __restrict__ f,
                                                 float* __restrict__ sq) {
    const int wave = threadIdx.x >> 6;
    const int lane = threadIdx.x & 63;
    const int row  = blockIdx.x * 4 + wave;
    const float4* rp = reinterpret_cast<const float4*>(f + (size_t)row * Cc);
    float4 v0 = rp[lane * 2 + 0];
    float4 v1 = rp[lane * 2 + 1];
    float s = v0.x * v0.x + v0.y * v0.y + v0.z * v0.z + v0.w * v0.w +
              v1.x * v1.x + v1.y * v1.y + v1.z * v1.z + v1.w * v1.w;
    #pragma unroll
    for (int off = 32; off > 0; off >>= 1) s += __shfl_down(s, off, 64);
    if (lane == 0) sq[row] = s;
}

__global__ __launch_bounds__(256) void pair_fp32(const float* __restrict__ f,
                                                 const int* __restrict__ tgt,
                                                 const float* __restrict__ sq,
                                                 double* __restrict__ partials) {
    int rem = blockIdx.x, br = 0;
    while (rem >= NBLK1 - br) { rem -= NBLK1 - br; ++br; }
    const int bc = br + rem;

    __shared__ float As[BK1][LSTR];
    __shared__ float Bs[BK1][LSTR];
    __shared__ float red[256];

    const int tid  = threadIdx.x;
    const int tx   = tid & 15;
    const int ty   = tid >> 4;
    const int row0 = ty * 4;
    const int col0 = tx * 4;

    const float* abase = f + (size_t)br * BM1 * Cc;
    const float* bbase = f + (size_t)bc * BM1 * Cc;

    const int r0 = tid >> 3;
    const int kb = (tid & 7) * 4;

    float acc[4][4] = {};

    for (int k0 = 0; k0 < Cc; k0 += BK1) {
        float4 a0 = *reinterpret_cast<const float4*>(abase + (size_t)(r0)      * Cc + k0 + kb);
        float4 a1 = *reinterpret_cast<const float4*>(abase + (size_t)(r0 + 32) * Cc + k0 + kb);
        float4 b0 = *reinterpret_cast<const float4*>(bbase + (size_t)(r0)      * Cc + k0 + kb);
        float4 b1 = *reinterpret_cast<const float4*>(bbase + (size_t)(r0 + 32) * Cc + k0 + kb);
        __syncthreads();
        As[kb + 0][r0]      = a0.x; As[kb + 1][r0]      = a0.y;
        As[kb + 2][r0]      = a0.z; As[kb + 3][r0]      = a0.w;
        As[kb + 0][r0 + 32] = a1.x; As[kb + 1][r0 + 32] = a1.y;
        As[kb + 2][r0 + 32] = a1.z; As[kb + 3][r0 + 32] = a1.w;
        Bs[kb + 0][r0]      = b0.x; Bs[kb + 1][r0]      = b0.y;
        Bs[kb + 2][r0]      = b0.z; Bs[kb + 3][r0]      = b0.w;
        Bs[kb + 0][r0 + 32] = b1.x; Bs[kb + 1][r0 + 32] = b1.y;
        Bs[kb + 2][r0 + 32] = b1.z; Bs[kb + 3][r0 + 32] = b1.w;
        __syncthreads();
        #pragma unroll
        for (int k = 0; k < BK1; ++k) {
            float4 av = *reinterpret_cast<const float4*>(&As[k][row0]);
            float4 bv = *reinterpret_cast<const float4*>(&Bs[k][col0]);
            acc[0][0] = fmaf(av.x, bv.x, acc[0][0]);
            acc[0][1] = fmaf(av.x, bv.y, acc[0][1]);
            acc[0][2] = fmaf(av.x, bv.z, acc[0][2]);
            acc[0][3] = fmaf(av.x, bv.w, acc[0][3]);
            acc[1][0] = fmaf(av.y, bv.x, acc[1][0]);
            acc[1][1] = fmaf(av.y, bv.y, acc[1][1]);
            acc[1][2] = fmaf(av.y, bv.z, acc[1][2]);
            acc[1][3] = fmaf(av.y, bv.w, acc[1][3]);
            acc[2][0] = fmaf(av.z, bv.x, acc[2][0]);
            acc[2][1] = fmaf(av.z, bv.y, acc[2][1]);
            acc[2][2] = fmaf(av.z, bv.z, acc[2][2]);
            acc[2][3] = fmaf(av.z, bv.w, acc[2][3]);
            acc[3][0] = fmaf(av.w, bv.x, acc[3][0]);
            acc[3][1] = fmaf(av.w, bv.y, acc[3][1]);
            acc[3][2] = fmaf(av.w, bv.z, acc[3][2]);
            acc[3][3] = fmaf(av.w, bv.w, acc[3][3]);
        }
    }

    const int gi = br * BM1 + row0;
    const int gj = bc * BM1 + col0;
    float sqi[4], sqj[4];
    int   ti_[4], tj_[4];
    #pragma unroll
    for (int m = 0; m < 4; ++m) { sqi[m] = sq[gi + m]; ti_[m] = tgt[gi + m]; }
    #pragma unroll
    for (int n = 0; n < 4; ++n) { sqj[n] = sq[gj + n]; tj_[n] = tgt[gj + n]; }

    float pos = 0.f, neg = 0.f;
    #pragma unroll
    for (int m = 0; m < 4; ++m)
        #pragma unroll
        for (int n = 0; n < 4; ++n) {
            if (gi + m == gj + n) continue;
            float d = fmaxf(sqi[m] + sqj[n] - 2.0f * acc[m][n], 0.0f);
            if (ti_[m] == tj_[n]) pos += d;
            else if (d < 1.0f) { float t = MRG - sqrtf(d); neg += t * t; }
        }
    const float w = (br == bc) ? 1.0f : 2.0f;
    red[tid] = w * (pos + neg);
    __syncthreads();
    #pragma unroll
    for (int st = 128; st > 0; st >>= 1) {
        if (tid < st) red[tid] += red[tid + st];
        __syncthreads();
    }
    if (tid == 0) partials[blockIdx.x] = (double)red[0];
}

__global__ __launch_bounds__(256) void finish_kernel(const double* __restrict__ partials,
                                                     float* __restrict__ out, int n) {
    __shared__ double red[256];
    double s = 0.0;
    for (int i = threadIdx.x; i < n; i += 256) s += partials[i];
    red[threadIdx.x] = s;
    __syncthreads();
    #pragma unroll
    for (int st = 128; st > 0; st >>= 1) {
        if (threadIdx.x < st) red[threadIdx.x] += red[threadIdx.x + st];
        __syncthreads();
    }
    if (threadIdx.x == 0) {
        const double t = (double)Nn * (double)(Nn - 1);
        out[0] = (float)(red[0] / (2.0 * t));
    }
}

// ---------------------------------------------------------------- launch
extern "C" void kernel_launch(void* const* d_in, const int* in_sizes, int n_in,
                              void* d_out, int out_size, void* d_ws, size_t ws_size,
                              hipStream_t stream) {
    const float* f   = (const float*)d_in[0];
    const int*   tgt = (const int*)d_in[1];
    float*       out = (float*)d_out;

    // workspace layout (16B-aligned)
    const size_t off_fb32 = 0;                                     // 512 KB
    const size_t off_sq32 = off_fb32 + (size_t)Nn * KF * 2;        // 32 KB
    const size_t off_M    = off_sq32 + (size_t)Nn * 4;             // 51200*8 = 400 KB
    const size_t off_s2   = off_M    + (size_t)NBINS * 8;          // 100*8 (contiguous after M)
    const size_t off_cnt  = off_s2   + (size_t)128 * 8;            // 128*4
    const size_t off_msq  = off_cnt  + (size_t)128 * 4;            // 64*8
    const size_t off_neg  = off_msq  + (size_t)64 * 8;             // 2080*8
    const size_t needed   = off_neg  + (size_t)NPAIRS2 * 8;        // ~1 MB

    if (ws_size >= needed) {
        unsigned short* fb32 = (unsigned short*)((char*)d_ws + off_fb32);
        float*     sq32      = (float*)    ((char*)d_ws + off_sq32);
        long long* Mfix      = (long long*)((char*)d_ws + off_M);
        long long* s2fix     = (long long*)((char*)d_ws + off_s2);
        int*       cnt       = (int*)      ((char*)d_ws + off_cnt);
        double*    msqPart   = (double*)   ((char*)d_ws + off_msq);
        double*    negPart   = (double*)   ((char*)d_ws + off_neg);

        const int zgrid = (NBINS + NCLS + 255) / 256;   // zeros Mfix||s2fix + cnt
        hipLaunchKernelGGL(zero_kernel,    dim3(zgrid),   dim3(256), 0, stream, Mfix, cnt);
        hipLaunchKernelGGL(prep_kernel,    dim3(Nn / 4),  dim3(256), 0, stream, f, tgt, fb32, sq32, Mfix, s2fix, cnt);
        hipLaunchKernelGGL(filter_kernel,  dim3(NPAIRS2), dim3(256), 0, stream, fb32, f, tgt, sq32, negPart);
        hipLaunchKernelGGL(msq_kernel,     dim3(64),      dim3(256), 0, stream, Mfix, msqPart);
        hipLaunchKernelGGL(finish2_kernel, dim3(1),       dim3(256), 0, stream, cnt, s2fix, msqPart, negPart, out);
    } else {
        float*  sq       = (float*)d_ws;
        double* partials = (double*)((char*)d_ws + (size_t)Nn * sizeof(float));

        hipLaunchKernelGGL(sq_kernel,     dim3(Nn / 4),  dim3(256), 0, stream, f, sq);
        hipLaunchKernelGGL(pair_fp32,     dim3(NPAIRS1), dim3(256), 0, stream, f, tgt, sq, partials);
        hipLaunchKernelGGL(finish_kernel, dim3(1),       dim3(256), 0, stream, partials, out, NPAIRS1);
    }
}

// Round 6
// 83.550 us; speedup vs baseline: 2.8386x; 2.8386x over previous
//
#include <hip/hip_runtime.h>
#include <math.h>
#include <stdint.h>

// ContrastiveLoss: N=8192, C=512, NC=100, MARGIN=1.0
// loss = (sum_{i!=j,same} d_ij + sum_{i!=j,diff} max(0, 1-sqrt(d_ij))^2) / (2*N*(N-1))
// d_ij = |xi|^2+|xj|^2-2 xi.xj (clamped at 0).
//
// Round 6: positive term analytic: sum_c [2 n_c S2_c - 2|M_c|^2].
//  - M class-sums: LDS int32 Q16 fire-and-forget atomics (ds_add, no chain,
//    no global atomics), per-chunk partials -> exact int64 reduce in msq.
//  - S2_c, n_c: LDS int64/int32 atomics inside finish (8192 ops).
// Negative term: K=32 bf16-MFMA lower-bound screen (thr 2.0 covers bf16
// rounding), exact fp32 recompute for rare candidates.
// All accumulation integer (commutative -> bit-deterministic) or fixed-order.

static constexpr int   Nn  = 8192;
static constexpr int   Cc  = 512;
static constexpr float MRG = 1.0f;
static constexpr int   KF  = 32;          // filter features
static constexpr float FILT_THR = 2.0f;   // margin^2 + bf16-error slack

static constexpr int NBLK2   = Nn / 128;                  // 64
static constexpr int NPAIRS2 = NBLK2 * (NBLK2 + 1) / 2;   // 2080
static constexpr int NCLS    = 100;
static constexpr int NBINS   = NCLS * Cc;                 // 51200

static constexpr int NCHUNK  = 64;        // row chunks (128 rows each)
static constexpr int QD      = 128;       // dims per quarter

static constexpr float SCALE_M  = 65536.0f;     // Q16 (int32 bins)
static constexpr float SCALE_S2 = 1048576.0f;   // Q20 (int64)

// ---- fp32 fallback config (small-ws path) ----
static constexpr int BM1     = 64;
static constexpr int BK1     = 32;
static constexpr int NBLK1   = Nn / BM1;
static constexpr int NPAIRS1 = NBLK1 * (NBLK1 + 1) / 2;
static constexpr int LSTR    = 68;

typedef __attribute__((ext_vector_type(8))) short short8v;
typedef __attribute__((ext_vector_type(4))) float f32x4;

static __device__ inline unsigned short f2bf(float x) {
    unsigned u = __float_as_uint(x);
    unsigned rnd = 0x7FFFu + ((u >> 16) & 1u);
    return (unsigned short)((u + rnd) >> 16);
}

// ---------------------------------------------------------------- prep: sq32, sqAll, fb32
__global__ __launch_bounds__(256) void prep_kernel(const float* __restrict__ f,
                                                   unsigned short* __restrict__ fb32,
                                                   float* __restrict__ sq32,
                                                   float* __restrict__ sqAll) {
    const int wave = threadIdx.x >> 6;
    const int lane = threadIdx.x & 63;
    const int row  = blockIdx.x * 4 + wave;
    const float4* rp = reinterpret_cast<const float4*>(f + (size_t)row * Cc);
    float4 v0 = rp[lane * 2 + 0];
    float4 v1 = rp[lane * 2 + 1];
    float s8 = v0.x * v0.x + v0.y * v0.y + v0.z * v0.z + v0.w * v0.w +
               v1.x * v1.x + v1.y * v1.y + v1.z * v1.z + v1.w * v1.w;
    if (lane < 4) {   // first 32 features -> bf16 for the filter
        short8v o;
        o[0] = (short)f2bf(v0.x); o[1] = (short)f2bf(v0.y);
        o[2] = (short)f2bf(v0.z); o[3] = (short)f2bf(v0.w);
        o[4] = (short)f2bf(v1.x); o[5] = (short)f2bf(v1.y);
        o[6] = (short)f2bf(v1.z); o[7] = (short)f2bf(v1.w);
        *reinterpret_cast<short8v*>(fb32 + (size_t)row * KF + lane * 8) = o;
    }
    float sAll = s8;
    float s32  = (lane < 4) ? s8 : 0.0f;
    #pragma unroll
    for (int off = 32; off > 0; off >>= 1) {
        sAll += __shfl_down(sAll, off, 64);
        s32  += __shfl_down(s32,  off, 64);
    }
    if (lane == 0) { sq32[row] = s32; sqAll[row] = sAll; }
}

// ---------------------------------------------------------------- class sums (LDS int atomics)
// block (chunk, quarter): 256 threads = 2 row-halves x 128 dims.
// bins[c][dim] int32 Q16 via ds_add (fire-and-forget, commutative).
__global__ __launch_bounds__(256) void clsum_kernel(const float* __restrict__ f,
                                                    const int* __restrict__ tgt,
                                                    int* __restrict__ partials) {
    const int chunk = blockIdx.x;    // 0..63
    const int q     = blockIdx.y;    // 0..3
    const int t     = threadIdx.x;
    const int dim   = t & (QD - 1);  // 0..127
    const int half  = t >> 7;        // 0/1

    __shared__ int bins[NCLS * QD];  // 51.2 KB
    for (int i = t; i < NCLS * QD; i += 256) bins[i] = 0;
    __syncthreads();

    const int r0 = chunk * 128 + half * 64;
    #pragma unroll 4
    for (int r = 0; r < 64; ++r) {
        const int row = r0 + r;
        const int c   = tgt[row];
        const float x = f[(size_t)row * Cc + q * QD + dim];
        const int  iq = (int)rintf(x * SCALE_M);
        atomicAdd(&bins[c * QD + dim], iq);
    }
    __syncthreads();

    // flush: partials[chunk][c*512 + q*128 + dim]
    int* dst = partials + (size_t)chunk * NBINS;
    for (int i = t; i < NCLS * QD; i += 256) {
        const int c = i >> 7, d = i & (QD - 1);
        dst[c * Cc + q * QD + d] = bins[i];
    }
}

// ---------------------------------------------------------------- sum_c |M_c|^2 partials
__global__ __launch_bounds__(256) void msq_kernel(const int* __restrict__ partials,
                                                  double* __restrict__ msqPart) {
    __shared__ double red[256];
    double local = 0.0;
    const int base = blockIdx.x * 800;            // 64 blocks x 800 = 51200 bins
    #pragma unroll
    for (int it = 0; it < 4; ++it) {
        const int idx = base + it * 256 + threadIdx.x;
        if (idx < base + 800 && idx < NBINS) {
            long long ws = 0;
            for (int ch = 0; ch < NCHUNK; ++ch)
                ws += (long long)partials[(size_t)ch * NBINS + idx];
            const double m = (double)ws * (1.0 / (double)SCALE_M);
            local += m * m;
        }
    }
    red[threadIdx.x] = local;
    __syncthreads();
    #pragma unroll
    for (int st = 128; st > 0; st >>= 1) {
        if (threadIdx.x < st) red[threadIdx.x] += red[threadIdx.x + st];
        __syncthreads();
    }
    if (threadIdx.x == 0) msqPart[blockIdx.x] = red[0];
}

// ---------------------------------------------------------------- hinge screen (K=32 bf16 MFMA)
__global__ __launch_bounds__(256) void filter_kernel(const unsigned short* __restrict__ fb32,
                                                     const float* __restrict__ f,
                                                     const int* __restrict__ tgt,
                                                     const float* __restrict__ sq32,
                                                     double* __restrict__ negPart) {
    int rem = blockIdx.x, br = 0;
    while (rem >= NBLK2 - br) { rem -= NBLK2 - br; ++br; }
    const int bc = br + rem;

    __shared__ unsigned short As[128][40];   // 80B row stride
    __shared__ unsigned short Bs[128][40];

    const int tid  = threadIdx.x;
    const int lane = tid & 63;
    const int wid  = tid >> 6;
    const int wr   = wid >> 1;
    const int wc   = wid & 1;

    #pragma unroll
    for (int it = 0; it < 2; ++it) {
        const int s   = tid + it * 256;     // 512 slots of 16B
        const int row = s >> 2, q = s & 3;
        short8v va = *reinterpret_cast<const short8v*>(fb32 + (size_t)(br * 128 + row) * KF + q * 8);
        short8v vb = *reinterpret_cast<const short8v*>(fb32 + (size_t)(bc * 128 + row) * KF + q * 8);
        *reinterpret_cast<short8v*>(&As[row][q * 8]) = va;
        *reinterpret_cast<short8v*>(&Bs[row][q * 8]) = vb;
    }
    __syncthreads();

    const f32x4 zero = {0.f, 0.f, 0.f, 0.f};
    short8v a[4], b[4];
    #pragma unroll
    for (int mf = 0; mf < 4; ++mf) {
        const int row = wr * 64 + mf * 16 + (lane & 15);
        a[mf] = *reinterpret_cast<const short8v*>(&As[row][(lane >> 4) * 8]);
    }
    #pragma unroll
    for (int nf = 0; nf < 4; ++nf) {
        const int row = wc * 64 + nf * 16 + (lane & 15);
        b[nf] = *reinterpret_cast<const short8v*>(&Bs[row][(lane >> 4) * 8]);
    }
    f32x4 acc[4][4];
    #pragma unroll
    for (int mf = 0; mf < 4; ++mf)
        #pragma unroll
        for (int nf = 0; nf < 4; ++nf)
            acc[mf][nf] = __builtin_amdgcn_mfma_f32_16x16x32_bf16(a[mf], b[nf], zero, 0, 0, 0);

    const int gi0 = br * 128 + wr * 64;
    const int gj0 = bc * 128 + wc * 64;

    float s32i[16]; int ti[16];
    #pragma unroll
    for (int mf = 0; mf < 4; ++mf)
        #pragma unroll
        for (int j = 0; j < 4; ++j) {
            const int r = gi0 + mf * 16 + (lane >> 4) * 4 + j;
            s32i[mf * 4 + j] = sq32[r];
            ti[mf * 4 + j]   = tgt[r];
        }
    float s32j[4]; int tj[4];
    #pragma unroll
    for (int nf = 0; nf < 4; ++nf) {
        const int c = gj0 + nf * 16 + (lane & 15);
        s32j[nf] = sq32[c];
        tj[nf]   = tgt[c];
    }

    float neg = 0.0f;
    #pragma unroll
    for (int mf = 0; mf < 4; ++mf)
        #pragma unroll
        for (int nf = 0; nf < 4; ++nf)
            #pragma unroll
            for (int j = 0; j < 4; ++j) {
                const int r = gi0 + mf * 16 + (lane >> 4) * 4 + j;
                const int c = gj0 + nf * 16 + (lane & 15);
                const float d32 = s32i[mf * 4 + j] + s32j[nf] - 2.0f * acc[mf][nf][j];
                if (r != c && ti[mf * 4 + j] != tj[nf] && d32 < FILT_THR) {
                    // exact full distance (fp32), rare path
                    const float4* xr = reinterpret_cast<const float4*>(f + (size_t)r * Cc);
                    const float4* xc = reinterpret_cast<const float4*>(f + (size_t)c * Cc);
                    float dd = 0.0f;
                    for (int k = 0; k < Cc / 4; ++k) {
                        float4 aa = xr[k], bb = xc[k];
                        float dx = aa.x - bb.x, dy = aa.y - bb.y;
                        float dz = aa.z - bb.z, dw = aa.w - bb.w;
                        dd += dx * dx + dy * dy + dz * dz + dw * dw;
                    }
                    const float t = (dd > 0.0f) ? (MRG - sqrtf(dd)) : MRG;
                    if (t > 0.0f) neg += t * t;
                }
            }

    __syncthreads();
    float* red = reinterpret_cast<float*>(As);
    const float w = (br == bc) ? 1.0f : 2.0f;
    red[tid] = w * neg;
    __syncthreads();
    #pragma unroll
    for (int st = 128; st > 0; st >>= 1) {
        if (tid < st) red[tid] += red[tid + st];
        __syncthreads();
    }
    if (tid == 0) negPart[blockIdx.x] = (double)red[0];
}

// ---------------------------------------------------------------- final combine
__global__ __launch_bounds__(256) void finish3_kernel(const int* __restrict__ tgt,
                                                      const float* __restrict__ sqAll,
                                                      const double* __restrict__ msqPart,
                                                      const double* __restrict__ negPart,
                                                      float* __restrict__ out) {
    __shared__ unsigned long long s2b[NCLS];
    __shared__ int cb[NCLS];
    __shared__ double red[256];
    const int t = threadIdx.x;
    if (t < NCLS) { s2b[t] = 0ULL; cb[t] = 0; }
    __syncthreads();

    for (int i = t; i < Nn; i += 256) {
        const int c = tgt[i];
        atomicAdd(&s2b[c], (unsigned long long)(long long)(sqAll[i] * SCALE_S2));
        atomicAdd(&cb[c], 1);
    }
    __syncthreads();

    double pa = 0.0;
    if (t < NCLS) {
        const double n  = (double)cb[t];
        const double s2 = (double)(long long)s2b[t] * (1.0 / (double)SCALE_S2);
        pa = 2.0 * n * s2;
    }
    double msum = (t < 64) ? msqPart[t] : 0.0;
    double nsum = 0.0;
    for (int i = t; i < NPAIRS2; i += 256) nsum += negPart[i];
    red[t] = pa - 2.0 * msum + nsum;
    __syncthreads();
    #pragma unroll
    for (int st = 128; st > 0; st >>= 1) {
        if (t < st) red[t] += red[t + st];
        __syncthreads();
    }
    if (t == 0) {
        const double T = (double)Nn * (double)(Nn - 1);
        out[0] = (float)(red[0] / (2.0 * T));
    }
}

// ---------------------------------------------------------------- fp32 fallback (round 1)
__global__ __launch_bounds__(256) void sq_kernel(const float* __restrict__ f,
                                                 float* __restrict__ sq) {
    const int wave = threadIdx.x >> 6;
    const int lane = threadIdx.x & 63;
    const int row  = blockIdx.x * 4 + wave;
    const float4* rp = reinterpret_cast<const float4*>(f + (size_t)row * Cc);
    float4 v0 = rp[lane * 2 + 0];
    float4 v1 = rp[lane * 2 + 1];
    float s = v0.x * v0.x + v0.y * v0.y + v0.z * v0.z + v0.w * v0.w +
              v1.x * v1.x + v1.y * v1.y + v1.z * v1.z + v1.w * v1.w;
    #pragma unroll
    for (int off = 32; off > 0; off >>= 1) s += __shfl_down(s, off, 64);
    if (lane == 0) sq[row] = s;
}

__global__ __launch_bounds__(256) void pair_fp32(const float* __restrict__ f,
                                                 const int* __restrict__ tgt,
                                                 const float* __restrict__ sq,
                                                 double* __restrict__ partials) {
    int rem = blockIdx.x, br = 0;
    while (rem >= NBLK1 - br) { rem -= NBLK1 - br; ++br; }
    const int bc = br + rem;

    __shared__ float As[BK1][LSTR];
    __shared__ float Bs[BK1][LSTR];
    __shared__ float red[256];

    const int tid  = threadIdx.x;
    const int tx   = tid & 15;
    const int ty   = tid >> 4;
    const int row0 = ty * 4;
    const int col0 = tx * 4;

    const float* abase = f + (size_t)br * BM1 * Cc;
    const float* bbase = f + (size_t)bc * BM1 * Cc;

    const int r0 = tid >> 3;
    const int kb = (tid & 7) * 4;

    float acc[4][4] = {};

    for (int k0 = 0; k0 < Cc; k0 += BK1) {
        float4 a0 = *reinterpret_cast<const float4*>(abase + (size_t)(r0)      * Cc + k0 + kb);
        float4 a1 = *reinterpret_cast<const float4*>(abase + (size_t)(r0 + 32) * Cc + k0 + kb);
        float4 b0 = *reinterpret_cast<const float4*>(bbase + (size_t)(r0)      * Cc + k0 + kb);
        float4 b1 = *reinterpret_cast<const float4*>(bbase + (size_t)(r0 + 32) * Cc + k0 + kb);
        __syncthreads();
        As[kb + 0][r0]      = a0.x; As[kb + 1][r0]      = a0.y;
        As[kb + 2][r0]      = a0.z; As[kb + 3][r0]      = a0.w;
        As[kb + 0][r0 + 32] = a1.x; As[kb + 1][r0 + 32] = a1.y;
        As[kb + 2][r0 + 32] = a1.z; As[kb + 3][r0 + 32] = a1.w;
        Bs[kb + 0][r0]      = b0.x; Bs[kb + 1][r0]      = b0.y;
        Bs[kb + 2][r0]      = b0.z; Bs[kb + 3][r0]      = b0.w;
        Bs[kb + 0][r0 + 32] = b1.x; Bs[kb + 1][r0 + 32] = b1.y;
        Bs[kb + 2][r0 + 32] = b1.z; Bs[kb + 3][r0 + 32] = b1.w;
        __syncthreads();
        #pragma unroll
        for (int k = 0; k < BK1; ++k) {
            float4 av = *reinterpret_cast<const float4*>(&As[k][row0]);
            float4 bv = *reinterpret_cast<const float4*>(&Bs[k][col0]);
            acc[0][0] = fmaf(av.x, bv.x, acc[0][0]);
            acc[0][1] = fmaf(av.x, bv.y, acc[0][1]);
            acc[0][2] = fmaf(av.x, bv.z, acc[0][2]);
            acc[0][3] = fmaf(av.x, bv.w, acc[0][3]);
            acc[1][0] = fmaf(av.y, bv.x, acc[1][0]);
            acc[1][1] = fmaf(av.y, bv.y, acc[1][1]);
            acc[1][2] = fmaf(av.y, bv.z, acc[1][2]);
            acc[1][3] = fmaf(av.y, bv.w, acc[1][3]);
            acc[2][0] = fmaf(av.z, bv.x, acc[2][0]);
            acc[2][1] = fmaf(av.z, bv.y, acc[2][1]);
            acc[2][2] = fmaf(av.z, bv.z, acc[2][2]);
            acc[2][3] = fmaf(av.z, bv.w, acc[2][3]);
            acc[3][0] = fmaf(av.w, bv.x, acc[3][0]);
            acc[3][1] = fmaf(av.w, bv.y, acc[3][1]);
            acc[3][2] = fmaf(av.w, bv.z, acc[3][2]);
            acc[3][3] = fmaf(av.w, bv.w, acc[3][3]);
        }
    }

    const int gi = br * BM1 + row0;
    const int gj = bc * BM1 + col0;
    float sqi[4], sqj[4];
    int   ti_[4], tj_[4];
    #pragma unroll
    for (int m = 0; m < 4; ++m) { sqi[m] = sq[gi + m]; ti_[m] = tgt[gi + m]; }
    #pragma unroll
    for (int n = 0; n < 4; ++n) { sqj[n] = sq[gj + n]; tj_[n] = tgt[gj + n]; }

    float pos = 0.f, neg = 0.f;
    #pragma unroll
    for (int m = 0; m < 4; ++m)
        #pragma unroll
        for (int n = 0; n < 4; ++n) {
            if (gi + m == gj + n) continue;
            float d = fmaxf(sqi[m] + sqj[n] - 2.0f * acc[m][n], 0.0f);
            if (ti_[m] == tj_[n]) pos += d;
            else if (d < 1.0f) { float t = MRG - sqrtf(d); neg += t * t; }
        }
    const float w = (br == bc) ? 1.0f : 2.0f;
    red[tid] = w * (pos + neg);
    __syncthreads();
    #pragma unroll
    for (int st = 128; st > 0; st >>= 1) {
        if (tid < st) red[tid] += red[tid + st];
        __syncthreads();
    }
    if (tid == 0) partials[blockIdx.x] = (double)red[0];
}

__global__ __launch_bounds__(256) void finish_kernel(const double* __restrict__ partials,
                                                     float* __restrict__ out, int n) {
    __shared__ double red[256];
    double s = 0.0;
    for (int i = threadIdx.x; i < n; i += 256) s += partials[i];
    red[threadIdx.x] = s;
    __syncthreads();
    #pragma unroll
    for (int st = 128; st > 0; st >>= 1) {
        if (threadIdx.x < st) red[threadIdx.x] += red[threadIdx.x + st];
        __syncthreads();
    }
    if (threadIdx.x == 0) {
        const double t = (double)Nn * (double)(Nn - 1);
        out[0] = (float)(red[0] / (2.0 * t));
    }
}

// ---------------------------------------------------------------- launch
extern "C" void kernel_launch(void* const* d_in, const int* in_sizes, int n_in,
                              void* d_out, int out_size, void* d_ws, size_t ws_size,
                              hipStream_t stream) {
    const float* f   = (const float*)d_in[0];
    const int*   tgt = (const int*)d_in[1];
    float*       out = (float*)d_out;

    // workspace layout (16B-aligned)
    const size_t off_fb32  = 0;                                      // 512 KB
    const size_t off_sq32  = off_fb32  + (size_t)Nn * KF * 2;        // 32 KB
    const size_t off_sqAll = off_sq32  + (size_t)Nn * 4;             // 32 KB
    const size_t off_part  = off_sqAll + (size_t)Nn * 4;             // 64*51200*4 = 13.1 MB
    const size_t off_msq   = off_part  + (size_t)NCHUNK * NBINS * 4; // 64*8
    const size_t off_neg   = off_msq   + (size_t)64 * 8;             // 2080*8
    const size_t needed    = off_neg   + (size_t)NPAIRS2 * 8;        // ~14 MB

    if (ws_size >= needed) {
        unsigned short* fb32 = (unsigned short*)((char*)d_ws + off_fb32);
        float*  sq32         = (float*) ((char*)d_ws + off_sq32);
        float*  sqAll        = (float*) ((char*)d_ws + off_sqAll);
        int*    partials     = (int*)   ((char*)d_ws + off_part);
        double* msqPart      = (double*)((char*)d_ws + off_msq);
        double* negPart      = (double*)((char*)d_ws + off_neg);

        hipLaunchKernelGGL(clsum_kernel,   dim3(NCHUNK, 4), dim3(256), 0, stream, f, tgt, partials);
        hipLaunchKernelGGL(prep_kernel,    dim3(Nn / 4),    dim3(256), 0, stream, f, fb32, sq32, sqAll);
        hipLaunchKernelGGL(filter_kernel,  dim3(NPAIRS2),   dim3(256), 0, stream, fb32, f, tgt, sq32, negPart);
        hipLaunchKernelGGL(msq_kernel,     dim3(64),        dim3(256), 0, stream, partials, msqPart);
        hipLaunchKernelGGL(finish3_kernel, dim3(1),         dim3(256), 0, stream, tgt, sqAll, msqPart, negPart, out);
    } else {
        float*  sq       = (float*)d_ws;
        double* partials = (double*)((char*)d_ws + (size_t)Nn * sizeof(float));

        hipLaunchKernelGGL(sq_kernel,     dim3(Nn / 4),  dim3(256), 0, stream, f, sq);
        hipLaunchKernelGGL(pair_fp32,     dim3(NPAIRS1), dim3(256), 0, stream, f, tgt, sq, partials);
        hipLaunchKernelGGL(finish_kernel, dim3(1),       dim3(256), 0, stream, partials, out, NPAIRS1);
    }
}